// Round 1
// baseline (189.709 us; speedup 1.0000x reference)
//
#include <hip/hip_runtime.h>

// MultiEmbed: joint = emb_t[t] + emb_l[l] + emb_u[u]  (B,N,E)
//             delta = lerp4(tables[mask], mat)        (B,N,N,E)
// Pure memory-bound write stream (~135 MB out). One fused kernel.

#define HOURS 168
#define BB 32
#define NN 128
#define EE 64
#define JOINT_ELEMS (BB * NN * EE)          // 262144 floats
#define JOINT4      (JOINT_ELEMS / 4)       // 65536 float4 work items
#define DELTA4      (BB * NN * NN * EE / 4) // 8388608 float4 work items
#define TOTAL4      (JOINT4 + DELTA4)

__device__ __forceinline__ float4 ld4(const float* p) {
    return *(const float4*)p;
}
__device__ __forceinline__ float4 f4add(float4 a, float4 b) {
    return make_float4(a.x + b.x, a.y + b.y, a.z + b.z, a.w + b.w);
}
__device__ __forceinline__ float4 f4sub(float4 a, float4 b) {
    return make_float4(a.x - b.x, a.y - b.y, a.z - b.z, a.w - b.w);
}
__device__ __forceinline__ float4 f4fma(float s, float4 a, float4 b) {
    return make_float4(fmaf(s, a.x, b.x), fmaf(s, a.y, b.y),
                       fmaf(s, a.z, b.z), fmaf(s, a.w, b.w));
}
__device__ __forceinline__ float4 f4sel(bool m, float4 a, float4 b) {
    // m ? a : b, per-component cndmask
    return make_float4(m ? a.x : b.x, m ? a.y : b.y, m ? a.z : b.z, m ? a.w : b.w);
}

__global__ __launch_bounds__(256) void multiembed_kernel(
    const int*   __restrict__ traj,     // (B,N,3)
    const float* __restrict__ mat,      // (B,N,N,2)
    const int*   __restrict__ traj_len, // (B,)
    const float* __restrict__ emb_t,    // (169,E)
    const float* __restrict__ emb_l,    // (100000,E)
    const float* __restrict__ emb_u,    // (10000,E)
    const float* __restrict__ emb_su,   // (2,E)
    const float* __restrict__ emb_sl,   // (2,E)
    const float* __restrict__ emb_tu,   // (2,E)
    const float* __restrict__ emb_tl,   // (2,E)
    float*       __restrict__ out)      // joint (262144) then delta (33554432)
{
    const int tid    = blockIdx.x * blockDim.x + threadIdx.x;
    const int stride = gridDim.x * blockDim.x;   // multiple of 16 by construction
    const int e      = (tid & 15) * 4;           // fixed E-slot for this thread

    // Preload the four 2xE tables at this thread's E-slot and fold into
    // the lerp form: delta = base[m] + (ds/100)*d1[m] + (dt/1000)*d2[m]
    const float4 sl0 = ld4(emb_sl + e),      sl1 = ld4(emb_sl + EE + e);
    const float4 su0 = ld4(emb_su + e),      su1 = ld4(emb_su + EE + e);
    const float4 tl0 = ld4(emb_tl + e),      tl1 = ld4(emb_tl + EE + e);
    const float4 tu0 = ld4(emb_tu + e),      tu1 = ld4(emb_tu + EE + e);

    const float4 base0 = f4add(sl0, tl0);
    const float4 base1 = f4add(sl1, tl1);
    const float4 d1_0  = f4sub(su0, sl0);
    const float4 d1_1  = f4sub(su1, sl1);
    const float4 d2_0  = f4sub(tu0, tl0);
    const float4 d2_1  = f4sub(tu1, tl1);

    float* const delta_out = out + JOINT_ELEMS;

    for (int q = tid; q < TOTAL4; q += stride) {
        if (q < JOINT4) {
            // ---- joint: gather three embedding rows ----
            const int cell = q >> 4;               // (b*N + n)
            const int u  = traj[cell * 3 + 0];
            const int l  = traj[cell * 3 + 1];
            const int t  = traj[cell * 3 + 2];
            int tm = (t - 1) % HOURS;              // python-style mod
            if (tm < 0) tm += HOURS;
            tm += 1;                               // 1..168
            float4 v = f4add(f4add(ld4(emb_t + tm * EE + e),
                                   ld4(emb_l + l  * EE + e)),
                             ld4(emb_u + u * EE + e));
            *(float4*)(out + q * 4) = v;
        } else {
            // ---- delta ----
            const int qd   = q - JOINT4;
            const int cell = qd >> 4;              // ((b*N + i)*N + j)
            const int j    = cell & (NN - 1);
            const int i    = (cell >> 7) & (NN - 1);
            const int b    = cell >> 14;
            const int L    = traj_len[b];
            const bool m   = (i < L) && (j < L);

            const float2 dd = *(const float2*)(mat + (size_t)cell * 2);
            const float csu = dd.x * 0.01f;    // ds / (SU-SL)
            const float ctu = dd.y * 0.001f;   // dt / (TU-TL)

            float4 r = f4sel(m, base1, base0);
            r = f4fma(csu, f4sel(m, d1_1, d1_0), r);
            r = f4fma(ctu, f4sel(m, d2_1, d2_0), r);

            *(float4*)(delta_out + qd * 4) = r;
        }
    }
}

extern "C" void kernel_launch(void* const* d_in, const int* in_sizes, int n_in,
                              void* d_out, int out_size, void* d_ws, size_t ws_size,
                              hipStream_t stream) {
    const int*   traj     = (const int*)  d_in[0];
    const float* mat      = (const float*)d_in[1];
    const int*   traj_len = (const int*)  d_in[2];
    const float* emb_t    = (const float*)d_in[3];
    const float* emb_l    = (const float*)d_in[4];
    const float* emb_u    = (const float*)d_in[5];
    const float* emb_su   = (const float*)d_in[6];
    const float* emb_sl   = (const float*)d_in[7];
    const float* emb_tu   = (const float*)d_in[8];
    const float* emb_tl   = (const float*)d_in[9];
    float*       out      = (float*)d_out;

    // 2048 blocks x 256 threads = 524288 threads (stride % 16 == 0),
    // ~16 float4 items per thread; 8 blocks/CU.
    multiembed_kernel<<<dim3(2048), dim3(256), 0, stream>>>(
        traj, mat, traj_len, emb_t, emb_l, emb_u,
        emb_su, emb_sl, emb_tu, emb_tl, out);
}

// Round 2
// 176.575 us; speedup vs baseline: 1.0744x; 1.0744x over previous
//
#include <hip/hip_runtime.h>

// MultiEmbed: joint = emb_t[t] + emb_l[l] + emb_u[u]  (B,N,E)   = 1 MB
//             delta = base[m] + (ds/100)*d1[m] + (dt/1000)*d2[m] (B,N,N,E) = 134 MB
// Write-stream memory-bound. Key structure exploited: with a grid-stride of
// 524288 float4 items, each thread's (i,j) within the N*N grid is
// loop-invariant and b is wave-uniform (+2 per iteration) -> mask collapses
// to a scalar-loaded compare, and most waves take a select-free uniform path.

#define HOURS 168
#define BB 32
#define NN 128
#define EE 64
#define JOINT_ELEMS (BB * NN * EE)            // 262144 floats
#define JOINT4      (JOINT_ELEMS / 4)         // 65536 float4 items
#define DELTA4      (BB * NN * NN * EE / 4)   // 8388608 float4 items
#define NBLOCKS     2048
#define NTHREADS    (NBLOCKS * 256)           // 524288 = grid stride
#define ITERS       (DELTA4 / NTHREADS)       // exactly 16, no remainder

typedef float f32x4 __attribute__((ext_vector_type(4)));

__device__ __forceinline__ f32x4 ld4(const float* p) {
    return *(const f32x4*)p;
}

__global__ __launch_bounds__(256) void multiembed_kernel(
    const int*   __restrict__ traj,     // (B,N,3)
    const float* __restrict__ mat,      // (B,N,N,2)
    const int*   __restrict__ traj_len, // (B,)
    const float* __restrict__ emb_t,    // (169,E)
    const float* __restrict__ emb_l,    // (100000,E)
    const float* __restrict__ emb_u,    // (10000,E)
    const float* __restrict__ emb_su,   // (2,E)
    const float* __restrict__ emb_sl,   // (2,E)
    const float* __restrict__ emb_tu,   // (2,E)
    const float* __restrict__ emb_tl,   // (2,E)
    float*       __restrict__ out)      // joint | delta, flat
{
    const int tid = blockIdx.x * blockDim.x + threadIdx.x;
    const int e   = (tid & 15) * 4;     // this thread's fixed E-slot

    // ---- preload the 2xE tables at this E-slot, folded into lerp form ----
    const f32x4 sl0 = ld4(emb_sl + e), sl1 = ld4(emb_sl + EE + e);
    const f32x4 su0 = ld4(emb_su + e), su1 = ld4(emb_su + EE + e);
    const f32x4 tl0 = ld4(emb_tl + e), tl1 = ld4(emb_tl + EE + e);
    const f32x4 tu0 = ld4(emb_tu + e), tu1 = ld4(emb_tu + EE + e);

    const f32x4 base0 = sl0 + tl0, base1 = sl1 + tl1;
    const f32x4 d1_0  = su0 - sl0, d1_1  = su1 - sl1;
    const f32x4 d2_0  = tu0 - tl0, d2_1  = tu1 - tl1;

    // ---- joint: first 65536 threads produce one float4 each ----
    if (tid < JOINT4) {
        const int cell = tid >> 4;              // b*N + n
        const int u = traj[cell * 3 + 0];
        const int l = traj[cell * 3 + 1];
        const int t = traj[cell * 3 + 2];
        int tm = (t - 1) % HOURS;               // python-style mod
        if (tm < 0) tm += HOURS;
        tm += 1;                                // 1..168
        f32x4 v = ld4(emb_t + tm * EE + e) + ld4(emb_l + (size_t)l * EE + e)
                + ld4(emb_u + (size_t)u * EE + e);
        __builtin_nontemporal_store(v, (f32x4*)(out + (size_t)tid * 4));
    }

    // ---- delta: exactly 16 iterations per thread, stride NTHREADS ----
    const int cell0 = tid >> 4;                       // 0..32767
    // invariants: stride/16 = 32768 cells/iter; 32768 % 128 == 0 and
    // (32768>>7) % 128 == 0  =>  j and i are loop-invariant; b += 2 per iter.
    const int j  = cell0 & (NN - 1);
    const int i  = (cell0 >> 7) & (NN - 1);
    const int mx = (i > j) ? i : j;                   // m == (mx < L)
    // b0 is wave-uniform (64 consecutive tids span 4 consecutive cells,
    // and cell/16384 is constant across them) -> force scalar.
    const int b0 = __builtin_amdgcn_readfirstlane(cell0 >> 14);   // 0 or 1

    const float* mptr = mat + (size_t)cell0 * 2;      // +65536 floats/iter
    float*       dptr = out + JOINT_ELEMS + (size_t)tid * 4;  // +NTHREADS*4/iter

    int b = b0;
    #pragma unroll 4
    for (int k = 0; k < ITERS; ++k) {
        const int  L = traj_len[b];                   // scalar (b uniform)
        const bool m = mx < L;

        const float2 dd  = *(const float2*)mptr;      // 16 lanes broadcast
        const float  csu = dd.x * 0.01f;              // ds/(SU-SL)
        const float  ctu = dd.y * 0.001f;             // dt/(TU-TL)

        f32x4 bse, v1, v2;
        const unsigned long long bal = __ballot(m);
        if (bal == 0xFFFFFFFFFFFFFFFFull) {           // all-valid (common)
            bse = base1; v1 = d1_1; v2 = d2_1;
        } else if (bal == 0ull) {                     // all-invalid (common)
            bse = base0; v1 = d1_0; v2 = d2_0;
        } else {                                      // boundary wave (rare)
            bse = m ? base1 : base0;
            v1  = m ? d1_1  : d1_0;
            v2  = m ? d2_1  : d2_0;
        }

        const f32x4 r = bse + csu * v1 + ctu * v2;    // fp-contract -> fma
        __builtin_nontemporal_store(r, (f32x4*)dptr);

        b    += 2;
        mptr += 32768 * 2;
        dptr += (size_t)NTHREADS * 4;
    }
}

extern "C" void kernel_launch(void* const* d_in, const int* in_sizes, int n_in,
                              void* d_out, int out_size, void* d_ws, size_t ws_size,
                              hipStream_t stream) {
    const int*   traj     = (const int*)  d_in[0];
    const float* mat      = (const float*)d_in[1];
    const int*   traj_len = (const int*)  d_in[2];
    const float* emb_t    = (const float*)d_in[3];
    const float* emb_l    = (const float*)d_in[4];
    const float* emb_u    = (const float*)d_in[5];
    const float* emb_su   = (const float*)d_in[6];
    const float* emb_sl   = (const float*)d_in[7];
    const float* emb_tu   = (const float*)d_in[8];
    const float* emb_tl   = (const float*)d_in[9];
    float*       out      = (float*)d_out;

    multiembed_kernel<<<dim3(NBLOCKS), dim3(256), 0, stream>>>(
        traj, mat, traj_len, emb_t, emb_l, emb_u,
        emb_su, emb_sl, emb_tu, emb_tl, out);
}